// Round 11
// baseline (436.051 us; speedup 1.0000x reference)
//
#include <hip/hip_runtime.h>

typedef unsigned short u16;
typedef __bf16 bf16x8 __attribute__((ext_vector_type(8)));
typedef float f32x4 __attribute__((ext_vector_type(4)));

__device__ __forceinline__ u16 f2bf(float f) {
  unsigned u = __builtin_bit_cast(unsigned, f);
  u += 0x7FFFu + ((u >> 16) & 1u);
  return (u16)(u >> 16);
}

#define GLOAD16(g, l) __builtin_amdgcn_global_load_lds( \
    (const __attribute__((address_space(1))) unsigned int*)(const void*)(g), \
    (__attribute__((address_space(3))) unsigned int*)(void*)(l), 16, 0, 0)

// swizzled u16 index of 16B-chunk c (0..7) in row r of a 64-u16-wide LDS tile
#define SW(r, c) (((r) << 6) + ((((c) ^ ((r) & 7))) << 3))

// q pre-scale: 1/sqrt(1024) * log2(e)  (exp -> exp2 folding)
#define QSCALE 0.045084222393f

// ---------------------------------------------------------------- transpose + f32->bf16
__global__ __launch_bounds__(256) void tconv(const float* __restrict__ W,
                                             u16* __restrict__ Wt, int K, int N) {
  __shared__ float t[32][33];
  int n0 = blockIdx.x * 32, k0 = blockIdx.y * 32;
  int tx = threadIdx.x, ty = threadIdx.y;
#pragma unroll
  for (int j = 0; j < 4; ++j)
    t[ty + j * 8][tx] = W[(size_t)(k0 + ty + j * 8) * N + n0 + tx];
  __syncthreads();
#pragma unroll
  for (int j = 0; j < 4; ++j)
    Wt[(size_t)(n0 + ty + j * 8) * K + k0 + tx] = f2bf(t[tx][ty + j * 8]);
}

// ---------------------------------------------------------------- posenc + layernorm
template <bool PE>
__global__ __launch_bounds__(256) void ln_row(const float* __restrict__ in,
                                              const float* __restrict__ g,
                                              const float* __restrict__ be,
                                              float* __restrict__ xout,
                                              u16* __restrict__ hout) {
  const int row = blockIdx.x;
  const int tid = threadIdx.x;
  const int s = row & 2047;
  float4 xv = *(const float4*)&in[(size_t)row * 1024 + tid * 4];
  float vals[4];
  const float* xp = (const float*)&xv;
#pragma unroll
  for (int j = 0; j < 4; ++j) {
    float v = xp[j];
    if (PE) {
      int d = tid * 4 + j;
      float freq = powf(10000.f, -2.f * (float)d * (1.f / 1024.f));
      float ang = (float)s * freq;
      v += (d & 1) ? cosf(ang) : sinf(ang);
    }
    vals[j] = v;
  }
  if (PE) {
    float4 st;
    float* sp = (float*)&st;
#pragma unroll
    for (int j = 0; j < 4; ++j) sp[j] = vals[j];
    *(float4*)&xout[(size_t)row * 1024 + tid * 4] = st;
  }
  float sum = vals[0] + vals[1] + vals[2] + vals[3];
  float sq = vals[0] * vals[0] + vals[1] * vals[1] + vals[2] * vals[2] + vals[3] * vals[3];
#pragma unroll
  for (int d = 1; d < 64; d <<= 1) {
    sum += __shfl_xor(sum, d);
    sq += __shfl_xor(sq, d);
  }
  __shared__ float red[8];
  int wave = tid >> 6, lane = tid & 63;
  if (lane == 0) { red[wave] = sum; red[4 + wave] = sq; }
  __syncthreads();
  sum = red[0] + red[1] + red[2] + red[3];
  sq = red[4] + red[5] + red[6] + red[7];
  float mu = sum * (1.f / 1024.f);
  float var = sq * (1.f / 1024.f) - mu * mu;
  float rv = rsqrtf(var + 1e-5f);
#pragma unroll
  for (int j = 0; j < 4; ++j) {
    int d = tid * 4 + j;
    hout[(size_t)row * 1024 + d] = f2bf((vals[j] - mu) * rv * g[d] + be[d]);
  }
}

// ---------------------------------------------------------------- GEMM  C = A @ Bt^T
// A: M x K bf16 row-major.  Bt: N x K bf16 row-major.  128x128 tile, BK=64, 4 waves.
// (R10 structure: swizzled 64-u16 rows, pre-swizzled gload source, 0 conflicts.)
#define EPI_QKV 0
#define EPI_OPROJ 1
#define EPI_FFN1 2
#define EPI_FFN2 3

template <int EPI>
__global__ __launch_bounds__(256, 2) void gemm_bt(
    const u16* __restrict__ A, const u16* __restrict__ Bt, int M, int N, int K,
    const float* __restrict__ bias, const float* __restrict__ resid,
    float* __restrict__ outf, u16* __restrict__ outb,
    u16* __restrict__ oq, u16* __restrict__ okk, u16* __restrict__ ovt) {
  __shared__ __align__(16) u16 As[128 * 64];
  __shared__ __align__(16) u16 Bs[128 * 64];
  const int tid = threadIdx.x;
  const int wave = tid >> 6, lane = tid & 63;
  const int m0 = blockIdx.y * 128, n0 = blockIdx.x * 128;
  const int lrow = lane & 15, lhi = lane >> 4;
  const int wr = (wave >> 1) * 64, wc = (wave & 1) * 64;
  const int srow = tid >> 3;
  const int swsrc = ((tid & 7) ^ (srow & 7)) * 8;
  const u16* Ag = A + (size_t)(m0 + srow) * K + swsrc;
  const u16* Bg = Bt + (size_t)(n0 + srow) * K + swsrc;

  f32x4 acc[4][4] = {};

  for (int kt = 0; kt < K; kt += 64) {
#pragma unroll
    for (int j = 0; j < 4; ++j) {
      GLOAD16(Ag + (size_t)(j * 32) * K + kt, &As[j * 2048 + wave * 512]);
      GLOAD16(Bg + (size_t)(j * 32) * K + kt, &Bs[j * 2048 + wave * 512]);
    }
    __syncthreads();
    bf16x8 af[2][4], bfr[2][4];
#pragma unroll
    for (int kk = 0; kk < 2; ++kk) {
#pragma unroll
      for (int m = 0; m < 4; ++m)
        af[kk][m] = *(const bf16x8*)&As[SW(wr + m * 16 + lrow, kk * 4 + lhi)];
#pragma unroll
      for (int n = 0; n < 4; ++n)
        bfr[kk][n] = *(const bf16x8*)&Bs[SW(wc + n * 16 + lrow, kk * 4 + lhi)];
    }
#pragma unroll
    for (int kk = 0; kk < 2; ++kk)
#pragma unroll
      for (int m = 0; m < 4; ++m)
#pragma unroll
        for (int n = 0; n < 4; ++n)
          acc[m][n] = __builtin_amdgcn_mfma_f32_16x16x32_bf16(af[kk][m], bfr[kk][n], acc[m][n], 0, 0, 0);
    __syncthreads();
  }

#pragma unroll
  for (int m = 0; m < 4; ++m) {
#pragma unroll
    for (int n = 0; n < 4; ++n) {
#pragma unroll
      for (int i = 0; i < 4; ++i) {
        int row = m0 + wr + m * 16 + lhi * 4 + i;
        int col = n0 + wc + n * 16 + lrow;
        float v = acc[m][n][i];
        if (EPI == EPI_QKV) {
          int which = col >> 10, c = col & 1023;
          int h = c >> 6, hd = c & 63;
          int b = row >> 11, s = row & 2047;
          size_t qk = (((size_t)(b * 16 + h) * 2048 + s) << 6) + hd;
          if (which == 0) oq[qk] = f2bf(v * QSCALE);
          else if (which == 1) okk[qk] = f2bf(v);
          else ovt[((size_t)(b * 16 + h) * 64 + hd) * 2048 + s] = f2bf(v);
        } else if (EPI == EPI_OPROJ) {
          size_t idx = (size_t)row * 1024 + col;
          outf[idx] = v + resid[idx];
        } else if (EPI == EPI_FFN1) {
          float t = v + bias[col];
          t = t > 0.f ? t : 0.01f * t;
          outb[(size_t)row * 3072 + col] = f2bf(t);
        } else {  // FFN2
          size_t idx = (size_t)row * 1024 + col;
          outf[idx] = v + bias[col] + resid[idx];
        }
      }
    }
  }
}

// ---------------------------------------------------------------- flash attention
// R6 structure (K/V LDS dbuf, 1 barrier/tile, XCD remap, no-max softmax) with:
// SWAPPED QK^T (mfma(K,Q) -> S^T): each lane holds 4 consecutive kv columns of
// P at fixed q-row -> packed P-write via v_cvt_pk_bf16_f32 + ds_write_b64
// (replaces 32 scalar f2bf + ds_write_b16 per tile).  exp2f with log2e folded
// into the q pre-scale (QSCALE).  PV unchanged.
__global__ __launch_bounds__(256, 3) void attn_fwd(const u16* __restrict__ qb,
                                                   const u16* __restrict__ kbuf,
                                                   const u16* __restrict__ vtb,
                                                   u16* __restrict__ ob) {
  __shared__ __align__(16) u16 Kl[2][64 * 64];
  __shared__ __align__(16) u16 Vl[2][64 * 64];
  __shared__ __align__(16) u16 Pl[128 * 64];
  const int tid = threadIdx.x, wave = tid >> 6, lane = tid & 63;
  const int wid = (blockIdx.x & 7) * 128 + (blockIdx.x >> 3);
  const int bh = wid >> 4, qt = wid & 15;
  const int lrow = lane & 15, lhi = lane >> 4;
  const u16* Qg = qb + (((size_t)bh * 2048 + qt * 128) << 6);
  const u16* Kg = kbuf + ((size_t)bh * 2048 << 6);
  const u16* Vg = vtb + (size_t)bh * 64 * 2048;
  const int srow = tid >> 3;
  const int swsrc = ((tid & 7) ^ (srow & 7)) * 8;

#pragma unroll
  for (int j = 0; j < 4; ++j)
    GLOAD16(Qg + (size_t)(srow + j * 32) * 64 + swsrc, &Pl[j * 2048 + wave * 512]);
#pragma unroll
  for (int j = 0; j < 2; ++j) {
    int r = srow + j * 32;
    GLOAD16(Kg + (size_t)r * 64 + swsrc, &Kl[0][j * 2048 + wave * 512]);
    GLOAD16(Vg + (size_t)r * 2048 + swsrc, &Vl[0][j * 2048 + wave * 512]);
  }
  __syncthreads();

  bf16x8 qf[2][2];
#pragma unroll
  for (int m = 0; m < 2; ++m)
#pragma unroll
    for (int kk = 0; kk < 2; ++kk)
      qf[m][kk] = *(const bf16x8*)&Pl[SW(wave * 32 + m * 16 + lrow, kk * 4 + lhi)];
  // Pl rows [32*wave, 32*wave+32) are wave-private from here on

  f32x4 oacc[2][4] = {};
  float lsum[2] = {0.f, 0.f};

  int cur = 0;
  for (int kv = 0; kv < 2048; kv += 64) {
    if (kv) __syncthreads();
    if (kv + 64 < 2048) {
#pragma unroll
      for (int j = 0; j < 2; ++j) {
        int r = srow + j * 32;
        GLOAD16(Kg + (size_t)(kv + 64 + r) * 64 + swsrc, &Kl[cur ^ 1][j * 2048 + wave * 512]);
        GLOAD16(Vg + (size_t)r * 2048 + kv + 64 + swsrc, &Vl[cur ^ 1][j * 2048 + wave * 512]);
      }
    }

    // swapped QK^T: sf[m][n][i] = S^T[kv=n*16+lhi*4+i][q=wave*32+m*16+lrow]
    f32x4 sf[2][4] = {};
#pragma unroll
    for (int n = 0; n < 4; ++n) {
#pragma unroll
      for (int kk = 0; kk < 2; ++kk) {
        bf16x8 kf = *(const bf16x8*)&Kl[cur][SW(n * 16 + lrow, kk * 4 + lhi)];
        sf[0][n] = __builtin_amdgcn_mfma_f32_16x16x32_bf16(kf, qf[0][kk], sf[0][n], 0, 0, 0);
        sf[1][n] = __builtin_amdgcn_mfma_f32_16x16x32_bf16(kf, qf[1][kk], sf[1][n], 0, 0, 0);
      }
    }
    // no-max softmax: p = exp2(s); pack pairs with cvt_pk; one b64 write per (m,n)
#pragma unroll
    for (int m = 0; m < 2; ++m) {
      const int pr = wave * 32 + m * 16 + lrow;
      const int prbase = pr << 6;
      float rs = 0.f;
#pragma unroll
      for (int n = 0; n < 4; ++n) {
        float p0 = exp2f(sf[m][n][0]);
        float p1 = exp2f(sf[m][n][1]);
        float p2 = exp2f(sf[m][n][2]);
        float p3 = exp2f(sf[m][n][3]);
        rs += (p0 + p1) + (p2 + p3);
        unsigned lo, hi;
        asm("v_cvt_pk_bf16_f32 %0, %1, %2" : "=v"(lo) : "v"(p0), "v"(p1));
        asm("v_cvt_pk_bf16_f32 %0, %1, %2" : "=v"(hi) : "v"(p2), "v"(p3));
        const int chunk = (n * 2 + (lhi >> 1)) ^ (pr & 7);
        uint2 pk;
        pk.x = lo;
        pk.y = hi;
        *(uint2*)&Pl[prbase + (chunk << 3) + ((lhi & 1) << 2)] = pk;
      }
      lsum[m] += rs;
    }
    // PV (unchanged; same-wave lgkmcnt orders P write->read)
#pragma unroll
    for (int kk = 0; kk < 2; ++kk) {
      bf16x8 pf0 = *(const bf16x8*)&Pl[SW(wave * 32 + 0 + lrow, kk * 4 + lhi)];
      bf16x8 pf1 = *(const bf16x8*)&Pl[SW(wave * 32 + 16 + lrow, kk * 4 + lhi)];
#pragma unroll
      for (int n = 0; n < 4; ++n) {
        bf16x8 vf = *(const bf16x8*)&Vl[cur][SW(n * 16 + lrow, kk * 4 + lhi)];
        oacc[0][n] = __builtin_amdgcn_mfma_f32_16x16x32_bf16(pf0, vf, oacc[0][n], 0, 0, 0);
        oacc[1][n] = __builtin_amdgcn_mfma_f32_16x16x32_bf16(pf1, vf, oacc[1][n], 0, 0, 0);
      }
    }
    cur ^= 1;
  }

  // lsum[m] currently: partial sums for q-row (wave*32+m*16+lrow), split over lhi
#pragma unroll
  for (int m = 0; m < 2; ++m) {
    lsum[m] += __shfl_xor(lsum[m], 16);
    lsum[m] += __shfl_xor(lsum[m], 32);
  }

  const int b = bh >> 4, h = bh & 15;
#pragma unroll
  for (int m = 0; m < 2; ++m)
#pragma unroll
    for (int i = 0; i < 4; ++i) {
      // PV output rows are q = m*16 + lhi*4 + i; fetch that row's lsum (held at
      // lane lrow' = lhi*4+i, uniform over lhi after the reduction above)
      float lq = __shfl(lsum[m], lhi * 4 + i, 64);
      float inv = 1.f / lq;
      int qrow = qt * 128 + wave * 32 + m * 16 + lhi * 4 + i;
#pragma unroll
      for (int n = 0; n < 4; ++n) {
        int hd = n * 16 + lrow;
        ob[((size_t)(b * 2048 + qrow)) * 1024 + h * 64 + hd] = f2bf(oacc[m][n][i] * inv);
      }
    }
}

// ---------------------------------------------------------------- launch
extern "C" void kernel_launch(void* const* d_in, const int* in_sizes, int n_in,
                              void* d_out, int out_size, void* d_ws, size_t ws_size,
                              hipStream_t stream) {
  const float* x = (const float*)d_in[0];
  const float* Wq = (const float*)d_in[1];
  const float* Wk = (const float*)d_in[2];
  const float* Wv = (const float*)d_in[3];
  const float* Wo = (const float*)d_in[4];
  const float* W1 = (const float*)d_in[5];
  const float* b1 = (const float*)d_in[6];
  const float* W2 = (const float*)d_in[7];
  const float* b2 = (const float*)d_in[8];
  const float* g1 = (const float*)d_in[9];
  const float* be1 = (const float*)d_in[10];
  const float* g2 = (const float*)d_in[11];
  const float* be2 = (const float*)d_in[12];

  char* ws = (char*)d_ws;
  const size_t MB = 1024 * 1024;
  float* x1 = (float*)(ws + 0);          // 32MB, becomes x2 in-place after OPROJ
  u16* h = (u16*)(ws + 32 * MB);         // 16MB (reused as h2)
  u16* q = (u16*)(ws + 48 * MB);         // 16MB
  u16* k = (u16*)(ws + 64 * MB);         // 16MB
  u16* vt = (u16*)(ws + 80 * MB);        // 16MB
  u16* o = (u16*)(ws + 96 * MB);         // 16MB
  u16* f = (u16*)(ws + 48 * MB);         // 48MB, aliases q/k/vt (dead after attn)
  u16* wqkv = (u16*)(ws + 112 * MB);     // 6MB
  u16* wo = (u16*)(ws + 118 * MB);       // 2MB
  u16* w1t = (u16*)(ws + 120 * MB);      // 6MB
  u16* w2t = (u16*)(ws + 126 * MB);      // 6MB -> 132MB total
  float* out = (float*)d_out;

  dim3 tb(32, 8);
  tconv<<<dim3(32, 32), tb, 0, stream>>>(Wq, wqkv, 1024, 1024);
  tconv<<<dim3(32, 32), tb, 0, stream>>>(Wk, wqkv + 1024 * 1024, 1024, 1024);
  tconv<<<dim3(32, 32), tb, 0, stream>>>(Wv, wqkv + 2 * 1024 * 1024, 1024, 1024);
  tconv<<<dim3(32, 32), tb, 0, stream>>>(Wo, wo, 1024, 1024);
  tconv<<<dim3(96, 32), tb, 0, stream>>>(W1, w1t, 1024, 3072);
  tconv<<<dim3(32, 96), tb, 0, stream>>>(W2, w2t, 3072, 1024);

  ln_row<true><<<8192, 256, 0, stream>>>(x, g1, be1, x1, h);

  gemm_bt<EPI_QKV><<<dim3(24, 64), 256, 0, stream>>>(h, wqkv, 8192, 3072, 1024,
                                                     nullptr, nullptr, nullptr, nullptr,
                                                     q, k, vt);
  attn_fwd<<<1024, 256, 0, stream>>>(q, k, vt, o);

  gemm_bt<EPI_OPROJ><<<dim3(8, 64), 256, 0, stream>>>(o, wo, 8192, 1024, 1024,
                                                      nullptr, x1, x1, nullptr,
                                                      nullptr, nullptr, nullptr);
  ln_row<false><<<8192, 256, 0, stream>>>(x1, g2, be2, nullptr, h);

  gemm_bt<EPI_FFN1><<<dim3(24, 64), 256, 0, stream>>>(h, w1t, 8192, 3072, 1024,
                                                      b1, nullptr, nullptr, f,
                                                      nullptr, nullptr, nullptr);
  gemm_bt<EPI_FFN2><<<dim3(8, 64), 256, 0, stream>>>(f, w2t, 8192, 1024, 3072,
                                                     b2, x1, out, nullptr,
                                                     nullptr, nullptr, nullptr);
}